// Round 16
// baseline (425.216 us; speedup 1.0000x reference)
//
#include <hip/hip_runtime.h>
#include <hip/hip_fp16.h>

#define S_LEN 2048
#define DKV 64
#define NBH 32
#define CTX_ELEMS ((size_t)NBH * S_LEN * DKV)

using half8 = __attribute__((ext_vector_type(8))) _Float16;
using half4 = __attribute__((ext_vector_type(4))) _Float16;
using f32x4 = __attribute__((ext_vector_type(4))) float;
using u32x4 = __attribute__((ext_vector_type(4))) unsigned int;

#define MFMA16x32(a, b, c) __builtin_amdgcn_mfma_f32_16x16x32_f16((a), (b), (c), 0, 0, 0)

// ---------------------------------------------------------------------------
// Runtime mask-dtype detection (1-byte bool vs 4-byte int/float 0/1).
// ---------------------------------------------------------------------------
__global__ void detect_mask_kernel(const unsigned char* __restrict__ mask,
                                   int* __restrict__ flag) {
  __shared__ int nz0s, nzos;
  if (threadIdx.x == 0) { nz0s = 0; nzos = 0; }
  __syncthreads();
  const u32x4* m = (const u32x4*)mask;
  unsigned int a0 = 0, ao = 0;
  for (int i = threadIdx.x; i < 8192; i += 512) {
    u32x4 v = m[i];
#pragma unroll
    for (int j = 0; j < 4; j++) {
      a0 |= v[j] & 0xffu;
      ao |= v[j] & 0xffffff00u;
    }
  }
  if (a0) atomicAdd(&nz0s, 1);
  if (ao) atomicAdd(&nzos, 1);
  __syncthreads();
  if (threadIdx.x == 0) *flag = (nz0s > 0 && nzos > 0) ? 0 : 1;
}

// ---------------------------------------------------------------------------
// Fused preprocessing v2:
//   blocks [0,2048)    : int32 mask -> exit immediately (main packs inline);
//                        byte mask  -> prepack mb words (fallback path)
//   blocks [2048,2176) : Q f32 -> f16 * 0.125 (grid-stride)
//   blocks [2176,2304) : K f32 -> f16        (grid-stride)
//   blocks [2304,3328) : V [bh][k][d] f32 -> VT [bh][d][k] f16
// mb layout: u32 at [((tile*2 + half)*16 + sp)*64 + lane]; within word,
// u16 per sub (sub01 = kt&1 of the sp pair), bits: e -> A row e col c,
// 4+e -> A col 16+c, 8+e -> B col c, 12+e -> B col 16+c.
// ---------------------------------------------------------------------------
#define PACK_B 2048
#define CONV_B 128
#define NF4 (NBH * S_LEN * DKV / 4)

__global__ void fused_pre_kernel(const void* __restrict__ maskv,
                                 const int* __restrict__ flag,
                                 unsigned int* __restrict__ mb,
                                 const float* __restrict__ Q, _Float16* __restrict__ QH,
                                 const float* __restrict__ K, _Float16* __restrict__ KH,
                                 const float* __restrict__ V, _Float16* __restrict__ VT) {
  __shared__ _Float16 t[64][68];
  const int bidx = blockIdx.x;
  const int tid = threadIdx.x;

  if (bidx < PACK_B) {
    if ((*flag) != 0) return;   // int32 mask: main kernel packs inline
    // ---------------- byte-mask prepack (correctness fallback) ------------
    const unsigned char* m8 = (const unsigned char*)maskv;
    const int bh = bidx >> 6;
    const int q0 = (bidx & 63) << 5;
    const unsigned char* m8b = m8 + (size_t)(bh * S_LEN + q0) * S_LEN;
    for (int idx = tid; idx < 2048; idx += 256) {
      const int lane = idx & 63;
      const int sph = idx >> 6;
      const int hf = sph >> 4;
      const int sp = sph & 15;
      const int g = lane >> 4;
      const int c = lane & 15;
      unsigned int mword = 0;
#pragma unroll
      for (int s01 = 0; s01 < 2; ++s01) {
        const int kt = hf * 32 + sp * 2 + s01;
        const unsigned char* mp = m8b + (size_t)(g * 4) * S_LEN + kt * 32 + c;
        unsigned int t16 = 0;
#pragma unroll
        for (int e = 0; e < 4; e++) {
          if (mp[(size_t)e * S_LEN]) t16 |= 1u << e;
          if (mp[(size_t)e * S_LEN + 16]) t16 |= 1u << (4 + e);
          if (mp[(size_t)(16 + e) * S_LEN]) t16 |= 1u << (8 + e);
          if (mp[(size_t)(16 + e) * S_LEN + 16]) t16 |= 1u << (12 + e);
        }
        mword |= t16 << (16 * s01);
      }
      mb[(((size_t)bidx * 2 + hf) * 16 + sp) * 64 + lane] = mword;
    }
  } else if (bidx < PACK_B + 2 * CONV_B) {
    // ---------------- Q/K fp32 -> fp16 (grid-stride) ----------------
    const bool isQ = bidx < PACK_B + CONV_B;
    const int cb = bidx - (isQ ? PACK_B : PACK_B + CONV_B);
    const float* src = isQ ? Q : K;
    _Float16* dst = isQ ? QH : KH;
    const float scale = isQ ? 0.125f : 1.0f;
    for (int i = cb * 256 + tid; i < NF4; i += CONV_B * 256) {
      f32x4 v = *(const f32x4*)(src + (size_t)i * 4);
      half4 h;
#pragma unroll
      for (int j = 0; j < 4; j++) h[j] = (_Float16)(v[j] * scale);
      *(half4*)(dst + (size_t)i * 4) = h;
    }
  } else {
    // ---------------- V transpose ----------------
    const int tIdx = bidx - (PACK_B + 2 * CONV_B);
    const int bh = tIdx >> 5;
    const int k0 = (tIdx & 31) * 64;
    const float* Vb = V + ((size_t)bh * S_LEN + k0) * DKV;
#pragma unroll
    for (int it = 0; it < 4; it++) {
      int idx = tid + it * 256;
      int kl = idx >> 4;
      int dq = (idx & 15) * 4;
      f32x4 v = *(const f32x4*)(Vb + (size_t)kl * DKV + dq);
#pragma unroll
      for (int j = 0; j < 4; j++) t[kl][dq + j] = (_Float16)v[j];
    }
    __syncthreads();
    _Float16* VTb = VT + (size_t)bh * DKV * S_LEN;
#pragma unroll
    for (int it = 0; it < 4; it++) {
      int idx = tid + it * 256;
      int d = idx >> 4;
      int kq = (idx & 15) * 4;
      half4 h;
#pragma unroll
      for (int j = 0; j < 4; j++) h[j] = t[kq + j][d];
      *(half4*)(VTb + (size_t)d * S_LEN + k0 + kq) = h;
    }
  }
}

// ---------------------------------------------------------------------------
// Main attention v12 = v10 structure + inline mask handling:
// pass 1 (int32 case) reads RAW mask coalesced (rides under pass-1's idle
// HBM), packs per-lane mb words for pass 2; pass 2 reads 1 dword per 2 subs.
// ---------------------------------------------------------------------------
#define LOADF(S, KT) { \
  const _Float16* kp_ = Kb + ((size_t)((KT) * 32 + c)) * DKV + g * 8; \
  k00##S = *(const half8*)kp_; \
  k01##S = *(const half8*)(kp_ + 32); \
  k10##S = *(const half8*)(kp_ + 16 * DKV); \
  k11##S = *(const half8*)(kp_ + 16 * DKV + 32); }

#define P1TESTW(KT, SH) { \
  const unsigned int* mp_ = m32b + (size_t)(KT) * 32 + c; \
  unsigned int t16_ = 0; \
  _Pragma("unroll") for (int e = 0; e < 4; e++) { \
    if (mp_[(size_t)e * S_LEN] != 0u)             t16_ |= 1u << e; \
    if (mp_[(size_t)e * S_LEN + 16] != 0u)        t16_ |= 1u << (4 + e); \
    if (mp_[(size_t)(16 + e) * S_LEN] != 0u)      t16_ |= 1u << (8 + e); \
    if (mp_[(size_t)(16 + e) * S_LEN + 16] != 0u) t16_ |= 1u << (12 + e); \
  } \
  mword |= t16_ << (SH); }

#define P1COMP(S, SH) { \
  f32x4 acA0 = (f32x4)0.0f, acA1 = (f32x4)0.0f; \
  f32x4 acB0 = (f32x4)0.0f, acB1 = (f32x4)0.0f; \
  acA0 = MFMA16x32(aA0, k00##S, acA0); \
  acA0 = MFMA16x32(aA1, k01##S, acA0); \
  acB0 = MFMA16x32(aB0, k00##S, acB0); \
  acB0 = MFMA16x32(aB1, k01##S, acB0); \
  acA1 = MFMA16x32(aA0, k10##S, acA1); \
  acA1 = MFMA16x32(aA1, k11##S, acA1); \
  acB1 = MFMA16x32(aB0, k10##S, acB1); \
  acB1 = MFMA16x32(aB1, k11##S, acB1); \
  _Pragma("unroll") for (int e = 0; e < 4; e++) { \
    float pA0 = ((mword >> ((SH) + e)) & 1u) ? 0.0f : __expf(acA0[e]); \
    float pA1 = ((mword >> ((SH) + 4 + e)) & 1u) ? 0.0f : __expf(acA1[e]); \
    float pB0 = ((mword >> ((SH) + 8 + e)) & 1u) ? 0.0f : __expf(acB0[e]); \
    float pB1 = ((mword >> ((SH) + 12 + e)) & 1u) ? 0.0f : __expf(acB1[e]); \
    ZsA[e] += pA0 + pA1; \
    ZsB[e] += pB0 + pB1; } }

#define P2COMP(KT, S, SH) { \
  half8 vb0 = *(const half8*)(Vb + (size_t)(0 * 16 + c) * S_LEN + (KT) * 32 + g * 8); \
  half8 vb1 = *(const half8*)(Vb + (size_t)(1 * 16 + c) * S_LEN + (KT) * 32 + g * 8); \
  half8 vb2 = *(const half8*)(Vb + (size_t)(2 * 16 + c) * S_LEN + (KT) * 32 + g * 8); \
  half8 vb3 = *(const half8*)(Vb + (size_t)(3 * 16 + c) * S_LEN + (KT) * 32 + g * 8); \
  f32x4 acA0 = (f32x4)0.0f, acA1 = (f32x4)0.0f; \
  f32x4 acB0 = (f32x4)0.0f, acB1 = (f32x4)0.0f; \
  acA0 = MFMA16x32(aA0, k00##S, acA0); \
  acA0 = MFMA16x32(aA1, k01##S, acA0); \
  acB0 = MFMA16x32(aB0, k00##S, acB0); \
  acB0 = MFMA16x32(aB1, k01##S, acB0); \
  acA1 = MFMA16x32(aA0, k10##S, acA1); \
  acA1 = MFMA16x32(aA1, k11##S, acA1); \
  acB1 = MFMA16x32(aB0, k10##S, acB1); \
  acB1 = MFMA16x32(aB1, k11##S, acB1); \
  _Pragma("unroll") for (int e = 0; e < 4; e++) { \
    float pA0 = ((mword >> ((SH) + e)) & 1u) ? 0.0f : __expf(acA0[e] - lZA[e]); \
    float pA1 = ((mword >> ((SH) + 4 + e)) & 1u) ? 0.0f : __expf(acA1[e] - lZA[e]); \
    float pB0 = ((mword >> ((SH) + 8 + e)) & 1u) ? 0.0f : __expf(acB0[e] - lZB[e]); \
    float pB1 = ((mword >> ((SH) + 12 + e)) & 1u) ? 0.0f : __expf(acB1[e] - lZB[e]); \
    pbuf[w][g * 4 + e][c] = (_Float16)pA0; \
    pbuf[w][g * 4 + e][16 + c] = (_Float16)pA1; \
    pbuf[w][16 + g * 4 + e][c] = (_Float16)pB0; \
    pbuf[w][16 + g * 4 + e][16 + c] = (_Float16)pB1; } \
  half8 paA = *(const half8*)&pbuf[w][c][g * 8]; \
  half8 paB = *(const half8*)&pbuf[w][16 + c][g * 8]; \
  _Pragma("unroll") for (int s = 0; s < 4; s++) { \
    const int r = (lane >> 3) + s * 8; \
    const int c4 = (lane & 7) * 4; \
    half4 h = *(const half4*)&pbuf[w][r][c4]; \
    f32x4 o; \
    _Pragma("unroll") for (int j = 0; j < 4; j++) o[j] = (float)h[j]; \
    __builtin_nontemporal_store(o, \
        (f32x4*)(attn_base + (size_t)r * S_LEN + (KT) * 32 + c4)); } \
  ctxA[0] = MFMA16x32(paA, vb0, ctxA[0]); \
  ctxB[0] = MFMA16x32(paB, vb0, ctxB[0]); \
  ctxA[1] = MFMA16x32(paA, vb1, ctxA[1]); \
  ctxB[1] = MFMA16x32(paB, vb1, ctxB[1]); \
  ctxA[2] = MFMA16x32(paA, vb2, ctxA[2]); \
  ctxB[2] = MFMA16x32(paB, vb2, ctxB[2]); \
  ctxA[3] = MFMA16x32(paA, vb3, ctxA[3]); \
  ctxB[3] = MFMA16x32(paB, vb3, ctxB[3]); }

__global__ __launch_bounds__(512, 2)
void attn_v12_kernel(const _Float16* __restrict__ QH, const _Float16* __restrict__ KH,
                     const _Float16* __restrict__ VT, const void* __restrict__ maskv,
                     unsigned int* __restrict__ mb, const int* __restrict__ flag,
                     float* __restrict__ out) {
  __shared__ __align__(16) _Float16 pbuf[8][32][40];
  __shared__ float zbuf[4][2][32];
  __shared__ __align__(16) float cbuf[4][32][64];

  const int tid = threadIdx.x;
  const int w = tid >> 6;
  const int lane = tid & 63;
  const int g = lane >> 4;
  const int c = lane & 15;
  const int tb = w >> 1;
  const int half = w & 1;

  const int phys = blockIdx.x;
  const int orig = (phys & 7) * 64 + (phys >> 3);
  const int tile = orig * 4 + tb;
  const int bh = tile >> 6;
  const int q0 = (tile & 63) << 5;

  const bool mask_w = (*flag) != 0;
  const unsigned int* m32b = (const unsigned int*)maskv +
                             (size_t)(bh * S_LEN + q0 + g * 4) * S_LEN;

  const _Float16* qpA = QH + ((size_t)(bh * S_LEN + q0 + c)) * DKV + g * 8;
  const half8 aA0 = *(const half8*)qpA;
  const half8 aA1 = *(const half8*)(qpA + 32);
  const _Float16* qpB = qpA + 16 * DKV;
  const half8 aB0 = *(const half8*)qpB;
  const half8 aB1 = *(const half8*)(qpB + 32);

  const _Float16* Kb = KH + (size_t)bh * S_LEN * DKV;
  const size_t mbbase = ((size_t)(tile * 2 + half) * 16) * 64 + lane;

  float ZsA[4] = {0.0f, 0.0f, 0.0f, 0.0f};
  float ZsB[4] = {0.0f, 0.0f, 0.0f, 0.0f};

  const int kt0 = half * 32;
  half8 k00a, k01a, k10a, k11a, k00b, k01b, k10b, k11b;

  // ---------------- pass 1: Z + inline mask pack, pipelined ----------------
  LOADF(a, kt0);
  for (int sp = 0; sp < 16; ++sp) {
    const int s0 = kt0 + sp * 2;
    LOADF(b, s0 + 1);
    unsigned int mword;
    if (mask_w) {
      mword = 0;
      P1TESTW(s0, 0);
      P1TESTW(s0 + 1, 16);
    } else {
      mword = mb[mbbase + (size_t)sp * 64];
    }
    P1COMP(a, 0);
    if (sp < 15) LOADF(a, s0 + 2);
    P1COMP(b, 16);
    if (mask_w) mb[mbbase + (size_t)sp * 64] = mword;
  }

#pragma unroll
  for (int off = 1; off < 16; off <<= 1) {
#pragma unroll
    for (int e = 0; e < 4; e++) {
      ZsA[e] += __shfl_xor(ZsA[e], off, 64);
      ZsB[e] += __shfl_xor(ZsB[e], off, 64);
    }
  }
  if (c == 0) {
#pragma unroll
    for (int e = 0; e < 4; e++) {
      zbuf[tb][half][g * 4 + e] = ZsA[e];
      zbuf[tb][half][16 + g * 4 + e] = ZsB[e];
    }
  }
  __syncthreads();
  float lZA[4], lZB[4];
#pragma unroll
  for (int e = 0; e < 4; e++) {
    lZA[e] = __logf(zbuf[tb][0][g * 4 + e] + zbuf[tb][1][g * 4 + e]);
    lZB[e] = __logf(zbuf[tb][0][16 + g * 4 + e] + zbuf[tb][1][16 + g * 4 + e]);
  }

  // ---------------- pass 2: attn = exp(s - lnZ), PV, pipelined -------------
  f32x4 ctxA[4], ctxB[4];
#pragma unroll
  for (int nn = 0; nn < 4; nn++) { ctxA[nn] = (f32x4)0.0f; ctxB[nn] = (f32x4)0.0f; }

  const _Float16* Vb = VT + (size_t)bh * DKV * S_LEN;
  float* attn_base = out + CTX_ELEMS + ((size_t)(bh * S_LEN + q0)) * S_LEN;

  LOADF(a, kt0);
  for (int sp = 0; sp < 16; ++sp) {
    const int s0 = kt0 + sp * 2;
    LOADF(b, s0 + 1);
    const unsigned int mword = mb[mbbase + (size_t)sp * 64];
    P2COMP(s0, a, 0);
    if (sp < 15) LOADF(a, s0 + 2);
    P2COMP(s0 + 1, b, 16);
  }

  // ---------------- ctx combine across the two halves ----------------------
  __syncthreads();
  if (half == 1) {
#pragma unroll
    for (int nn = 0; nn < 4; nn++) {
#pragma unroll
      for (int e = 0; e < 4; e++) {
        cbuf[tb][g * 4 + e][nn * 16 + c] = ctxA[nn][e];
        cbuf[tb][16 + g * 4 + e][nn * 16 + c] = ctxB[nn][e];
      }
    }
  }
  __syncthreads();
  if (half == 0) {
    float* cb = out + ((size_t)(bh * S_LEN + q0)) * DKV;
#pragma unroll
    for (int nn = 0; nn < 4; nn++) {
#pragma unroll
      for (int e = 0; e < 4; e++) {
        float vA = ctxA[nn][e] + cbuf[tb][g * 4 + e][nn * 16 + c];
        float vB = ctxB[nn][e] + cbuf[tb][16 + g * 4 + e][nn * 16 + c];
        __builtin_nontemporal_store(vA, cb + (size_t)(g * 4 + e) * DKV + nn * 16 + c);
        __builtin_nontemporal_store(vB, cb + (size_t)(16 + g * 4 + e) * DKV + nn * 16 + c);
      }
    }
  }
}

// ---------------------------------------------------------------------------
// Fallback (R1 kernel) if ws is too small.
// ---------------------------------------------------------------------------
__global__ __launch_bounds__(512, 1)
void attn_slow_kernel(const float* __restrict__ Q, const float* __restrict__ K,
                      const float* __restrict__ V, const void* __restrict__ maskv,
                      float* __restrict__ out, const int* __restrict__ flag) {
  __shared__ __align__(16) unsigned char smem[16 * 2056 * 2];
  __shared__ float redm[8][16];
  __shared__ float reds[8][16];
  _Float16 (*P)[2056] = (_Float16 (*)[2056])smem;

  const int bh = blockIdx.y;
  const int q0 = blockIdx.x << 4;
  const int tid = threadIdx.x;
  const int w = tid >> 6;
  const int lane = tid & 63;
  const int g = lane >> 4;
  const int c = lane & 15;
  const int k0 = w << 8;

  const bool mask_w = (*flag) != 0;
  const unsigned char* m8 = (const unsigned char*)maskv;
  const unsigned int* m32 = (const unsigned int*)maskv;

  const float* Qb = Q + ((size_t)bh * S_LEN + q0) * DKV;
  const float* Kb = K + (size_t)bh * S_LEN * DKV;
  const float* Vb = V + (size_t)bh * S_LEN * DKV;
  const size_t mbase = ((size_t)bh * S_LEN + q0) * S_LEN;
  float* ctx_out = out + ((size_t)bh * S_LEN + q0) * DKV;
  float* attn_out = out + CTX_ELEMS + mbase;

  half8 a0, a1;
  {
    const float* qrow = Qb + (size_t)c * DKV + g * 8;
    f32x4 x0 = *(const f32x4*)(qrow);
    f32x4 x1 = *(const f32x4*)(qrow + 4);
    f32x4 y0 = *(const f32x4*)(qrow + 32);
    f32x4 y1 = *(const f32x4*)(qrow + 36);
#pragma unroll
    for (int j = 0; j < 4; j++) {
      a0[j] = (_Float16)x0[j]; a0[4 + j] = (_Float16)x1[j];
      a1[j] = (_Float16)y0[j]; a1[4 + j] = (_Float16)y1[j];
    }
  }

  f32x4 acc[16];
#pragma unroll
  for (int n = 0; n < 16; n++) acc[n] = (f32x4)0.0f;
#pragma unroll
  for (int n = 0; n < 16; n++) {
    const float* kr = Kb + (size_t)(k0 + n * 16 + c) * DKV + g * 8;
    f32x4 x0 = *(const f32x4*)(kr);
    f32x4 x1 = *(const f32x4*)(kr + 4);
    f32x4 y0 = *(const f32x4*)(kr + 32);
    f32x4 y1 = *(const f32x4*)(kr + 36);
    half8 b0, b1;
#pragma unroll
    for (int j = 0; j < 4; j++) {
      b0[j] = (_Float16)x0[j]; b0[4 + j] = (_Float16)x1[j];
      b1[j] = (_Float16)y0[j]; b1[4 + j] = (_Float16)y1[j];
    }
    acc[n] = MFMA16x32(a0, b0, acc[n]);
    acc[n] = MFMA16x32(a1, b1, acc[n]);
  }

  float mx[4] = {-1e9f, -1e9f, -1e9f, -1e9f};
#pragma unroll
  for (int n = 0; n < 16; n++) {
    const int kc = k0 + n * 16 + c;
#pragma unroll
    for (int e = 0; e < 4; e++) {
      const size_t mi = mbase + (size_t)(g * 4 + e) * S_LEN + kc;
      bool masked;
      if (mask_w) masked = (__builtin_nontemporal_load(&m32[mi]) != 0u);
      else        masked = (__builtin_nontemporal_load(&m8[mi]) != 0);
      float s = masked ? -1e9f : acc[n][e] * 0.125f;
      acc[n][e] = s;
      mx[e] = fmaxf(mx[e], s);
    }
  }
#pragma unroll
  for (int off = 1; off < 16; off <<= 1) {
#pragma unroll
    for (int e = 0; e < 4; e++)
      mx[e] = fmaxf(mx[e], __shfl_xor(mx[e], off, 64));
  }
  if (c == 0) {
#pragma unroll
    for (int e = 0; e < 4; e++) redm[w][g * 4 + e] = mx[e];
  }
  __syncthreads();
  float m[4], sm[4];
#pragma unroll
  for (int e = 0; e < 4; e++) {
    float v = redm[0][g * 4 + e];
#pragma unroll
    for (int ww = 1; ww < 8; ww++) v = fmaxf(v, redm[ww][g * 4 + e]);
    m[e] = v;
    sm[e] = 0.0f;
  }
#pragma unroll
  for (int n = 0; n < 16; n++) {
#pragma unroll
    for (int e = 0; e < 4; e++) {
      float p = __expf(acc[n][e] - m[e]);
      acc[n][e] = p;
      sm[e] += p;
    }
  }
#pragma unroll
  for (int off = 1; off < 16; off <<= 1) {
#pragma unroll
    for (int e = 0; e < 4; e++) sm[e] += __shfl_xor(sm[e], off, 64);
  }
  if (c == 0) {
#pragma unroll
    for (int e = 0; e < 4; e++) reds[w][g * 4 + e] = sm[e];
  }
  __syncthreads();
  float inv[4];
#pragma unroll
  for (int e = 0; e < 4; e++) {
    float z = 0.0f;
#pragma unroll
    for (int ww = 0; ww < 8; ww++) z += reds[ww][g * 4 + e];
    inv[e] = 1.0f / z;
  }
#pragma unroll
  for (int n = 0; n < 16; n++) {
    const int kc = k0 + n * 16 + c;
#pragma unroll
    for (int e = 0; e < 4; e++) {
      float v = acc[n][e] * inv[e];
      __builtin_nontemporal_store(v, &attn_out[(size_t)(g * 4 + e) * S_LEN + kc]);
      P[g * 4 + e][kc] = (_Float16)v;
    }
  }
  __syncthreads();

  f32x4 ctx[4];
#pragma unroll
  for (int n = 0; n < 4; n++) ctx[n] = (f32x4)0.0f;
  for (int ks = 0; ks < 8; ks++) {
    const int kb = k0 + ks * 32;
    half8 pa = *(const half8*)&P[c][kb + g * 8];
#pragma unroll
    for (int n = 0; n < 4; n++) {
      const float* vp = Vb + (size_t)(kb + g * 8) * DKV + n * 16 + c;
      half8 vb;
#pragma unroll
      for (int j = 0; j < 8; j++) vb[j] = (_Float16)vp[(size_t)j * DKV];
      ctx[n] = MFMA16x32(pa, vb, ctx[n]);
    }
  }
  __syncthreads();

  float* red2 = (float*)smem;
#pragma unroll
  for (int n = 0; n < 4; n++) {
#pragma unroll
    for (int e = 0; e < 4; e++)
      red2[((w * 16) + g * 4 + e) * 64 + n * 16 + c] = ctx[n][e];
  }
  __syncthreads();
  for (int i = tid; i < 16 * 64; i += 512) {
    int q = i >> 6, d = i & 63;
    float ssum = 0.0f;
#pragma unroll
    for (int ww = 0; ww < 8; ww++) ssum += red2[((ww * 16) + q) * 64 + d];
    ctx_out[(size_t)q * DKV + d] = ssum;
  }
}

extern "C" void kernel_launch(void* const* d_in, const int* in_sizes, int n_in,
                              void* d_out, int out_size, void* d_ws, size_t ws_size,
                              hipStream_t stream) {
  (void)in_sizes; (void)n_in; (void)out_size;
  const float* Q = (const float*)d_in[0];
  const float* K = (const float*)d_in[1];
  const float* V = (const float*)d_in[2];
  const void* mask = d_in[3];

  const size_t HBYTES = (size_t)NBH * S_LEN * DKV * sizeof(_Float16);       // 8 MB
  const size_t MBBYTES = (size_t)2048 * 2 * 16 * 64 * 4;                    // 16 MB
  const size_t NEED = 256 + 3 * HBYTES + MBBYTES;

  int* flag = (int*)d_ws;
  hipLaunchKernelGGL(detect_mask_kernel, dim3(1), dim3(512), 0, stream,
                     (const unsigned char*)mask, flag);

  if (ws_size >= NEED) {
    _Float16* QH = (_Float16*)((char*)d_ws + 256);
    _Float16* KH = (_Float16*)((char*)d_ws + 256 + HBYTES);
    _Float16* VT = (_Float16*)((char*)d_ws + 256 + 2 * HBYTES);
    unsigned int* mb = (unsigned int*)((char*)d_ws + 256 + 3 * HBYTES);
    hipLaunchKernelGGL(fused_pre_kernel,
                       dim3(PACK_B + 2 * CONV_B + (S_LEN / 64) * NBH), dim3(256), 0, stream,
                       mask, flag, mb, Q, QH, K, KH, V, VT);
    hipLaunchKernelGGL(attn_v12_kernel, dim3(512), dim3(512), 0, stream,
                       QH, KH, VT, mask, mb, flag, (float*)d_out);
  } else {
    hipLaunchKernelGGL(attn_slow_kernel, dim3(128, 32), dim3(512), 0, stream,
                       Q, K, V, mask, (float*)d_out, flag);
  }
}

// Round 17
// 345.952 us; speedup vs baseline: 1.2291x; 1.2291x over previous
//
#include <hip/hip_runtime.h>
#include <hip/hip_fp16.h>

#define S_LEN 2048
#define DKV 64
#define NBH 32
#define CTX_ELEMS ((size_t)NBH * S_LEN * DKV)

using half8 = __attribute__((ext_vector_type(8))) _Float16;
using half4 = __attribute__((ext_vector_type(4))) _Float16;
using f32x4 = __attribute__((ext_vector_type(4))) float;
using u32x4 = __attribute__((ext_vector_type(4))) unsigned int;

#define MFMA16x32(a, b, c) __builtin_amdgcn_mfma_f32_16x16x32_f16((a), (b), (c), 0, 0, 0)

// ---------------------------------------------------------------------------
// Runtime mask-dtype detection (1-byte bool vs 4-byte int/float 0/1).
// ---------------------------------------------------------------------------
__global__ void detect_mask_kernel(const unsigned char* __restrict__ mask,
                                   int* __restrict__ flag) {
  __shared__ int nz0s, nzos;
  if (threadIdx.x == 0) { nz0s = 0; nzos = 0; }
  __syncthreads();
  const u32x4* m = (const u32x4*)mask;
  unsigned int a0 = 0, ao = 0;
  for (int i = threadIdx.x; i < 8192; i += 512) {
    u32x4 v = m[i];
#pragma unroll
    for (int j = 0; j < 4; j++) {
      a0 |= v[j] & 0xffu;
      ao |= v[j] & 0xffffff00u;
    }
  }
  if (a0) atomicAdd(&nz0s, 1);
  if (ao) atomicAdd(&nzos, 1);
  __syncthreads();
  if (threadIdx.x == 0) *flag = (nz0s > 0 && nzos > 0) ? 0 : 1;
}

// ---------------------------------------------------------------------------
// Fused preprocessing (proven R13): block-range role dispatch so the four
// independent jobs overlap on hardware (pack is HBM-read-bound; converts
// and the V-transpose hide in its shadow).
//   blocks [0,2048)    : pack mask -> bits (16B/lane loads + 3x shfl_xor)
//   blocks [2048,2176) : Q f32 -> f16 * 0.125 (grid-stride)
//   blocks [2176,2304) : K f32 -> f16        (grid-stride)
//   blocks [2304,3328) : V [bh][k][d] f32 -> VT [bh][d][k] f16
// ---------------------------------------------------------------------------
#define PACK_B 2048
#define CONV_B 128
#define NF4 (NBH * S_LEN * DKV / 4)   // float4s per tensor = 1048576

__global__ void fused_pre_kernel(const void* __restrict__ maskv,
                                 const int* __restrict__ flag,
                                 unsigned int* __restrict__ bits,
                                 const float* __restrict__ Q, _Float16* __restrict__ QH,
                                 const float* __restrict__ K, _Float16* __restrict__ KH,
                                 const float* __restrict__ V, _Float16* __restrict__ VT) {
  __shared__ unsigned char nib[256];
  __shared__ _Float16 t[64][68];
  const int bidx = blockIdx.x;
  const int tid = threadIdx.x;

  if (bidx < PACK_B) {
    // ---------------- mask pack ----------------
    const bool w4 = (*flag) != 0;
    const unsigned int* m32 = (const unsigned int*)maskv;
    if (w4) {
      const int w = tid >> 6;
      const int lane = tid & 63;
      for (int it = 0; it < 64; ++it) {
        const size_t wb = ((size_t)bidx * 64 + it) * 1024 + (size_t)w * 256;
        u32x4 v = __builtin_nontemporal_load((const u32x4*)(m32 + wb + lane * 4));
        unsigned int x = ((v[0] ? 1u : 0u) | (v[1] ? 2u : 0u) |
                          (v[2] ? 4u : 0u) | (v[3] ? 8u : 0u)) << ((lane & 7) * 4);
        x |= __shfl_xor(x, 1, 64);
        x |= __shfl_xor(x, 2, 64);
        x |= __shfl_xor(x, 4, 64);
        if ((lane & 7) == 0)
          bits[(wb >> 5) + (lane >> 3)] = x;
      }
    } else {
      for (int it = 0; it < 64; ++it) {
        const size_t e0 = ((size_t)bidx * 64 + it) * 1024;
        const size_t ei = e0 + (size_t)tid * 4;
        unsigned int b = __builtin_nontemporal_load(m32 + (ei >> 2));
        unsigned int nv = ((b & 0xffu) ? 1u : 0u) | ((b & 0xff00u) ? 2u : 0u) |
                          ((b & 0xff0000u) ? 4u : 0u) | ((b & 0xff000000u) ? 8u : 0u);
        __syncthreads();
        nib[tid] = (unsigned char)nv;
        __syncthreads();
        if (tid < 32) {
          unsigned int dw = 0;
#pragma unroll
          for (int tt = 0; tt < 8; ++tt)
            dw |= ((unsigned int)nib[tid * 8 + tt]) << (tt * 4);
          bits[(e0 >> 5) + tid] = dw;
        }
      }
    }
  } else if (bidx < PACK_B + 2 * CONV_B) {
    // ---------------- Q/K fp32 -> fp16 (grid-stride) ----------------
    const bool isQ = bidx < PACK_B + CONV_B;
    const int cb = bidx - (isQ ? PACK_B : PACK_B + CONV_B);
    const float* src = isQ ? Q : K;
    _Float16* dst = isQ ? QH : KH;
    const float scale = isQ ? 0.125f : 1.0f;
    for (int i = cb * 256 + tid; i < NF4; i += CONV_B * 256) {
      f32x4 v = *(const f32x4*)(src + (size_t)i * 4);
      half4 h;
#pragma unroll
      for (int j = 0; j < 4; j++) h[j] = (_Float16)(v[j] * scale);
      *(half4*)(dst + (size_t)i * 4) = h;
    }
  } else {
    // ---------------- V transpose ----------------
    const int tIdx = bidx - (PACK_B + 2 * CONV_B);
    const int bh = tIdx >> 5;
    const int k0 = (tIdx & 31) * 64;
    const float* Vb = V + ((size_t)bh * S_LEN + k0) * DKV;
#pragma unroll
    for (int it = 0; it < 4; it++) {
      int idx = tid + it * 256;
      int kl = idx >> 4;
      int dq = (idx & 15) * 4;
      f32x4 v = *(const f32x4*)(Vb + (size_t)kl * DKV + dq);
#pragma unroll
      for (int j = 0; j < 4; j++) t[kl][dq + j] = (_Float16)v[j];
    }
    __syncthreads();
    _Float16* VTb = VT + (size_t)bh * DKV * S_LEN;
#pragma unroll
    for (int it = 0; it < 4; it++) {
      int idx = tid + it * 256;
      int d = idx >> 4;
      int kq = (idx & 15) * 4;
      half4 h;
#pragma unroll
      for (int j = 0; j < 4; j++) h[j] = t[kq + j][d];
      *(half4*)(VTb + (size_t)d * S_LEN + k0 + kq) = h;
    }
  }
}

// ---------------------------------------------------------------------------
// Main attention v10 (proven R12/R13/R15): v9 + explicit 1-sub-lookahead
// K-fragment pipeline. Each wave owns a 32-row q-tile; 8 waves =
// 4 q32-tiles x 2 k-halves; no-max softmax; grid 512; lb(512,2) ->
// VGPR cap 128.
// ---------------------------------------------------------------------------
#define LOADF(S, KT) { \
  const _Float16* kp_ = Kb + ((size_t)((KT) * 32 + c)) * DKV + g * 8; \
  k00##S = *(const half8*)kp_; \
  k01##S = *(const half8*)(kp_ + 32); \
  k10##S = *(const half8*)(kp_ + 16 * DKV); \
  k11##S = *(const half8*)(kp_ + 16 * DKV + 32); }

#define P1SUB(KT, S) { \
  unsigned int mwA[4], mwB[4]; \
  _Pragma("unroll") for (int e = 0; e < 4; e++) { \
    mwA[e] = bq[(size_t)(g * 4 + e) * (S_LEN / 32) + (KT)]; \
    mwB[e] = bq[(size_t)(16 + g * 4 + e) * (S_LEN / 32) + (KT)]; } \
  f32x4 acA0 = (f32x4)0.0f, acA1 = (f32x4)0.0f; \
  f32x4 acB0 = (f32x4)0.0f, acB1 = (f32x4)0.0f; \
  acA0 = MFMA16x32(aA0, k00##S, acA0); \
  acA0 = MFMA16x32(aA1, k01##S, acA0); \
  acB0 = MFMA16x32(aB0, k00##S, acB0); \
  acB0 = MFMA16x32(aB1, k01##S, acB0); \
  acA1 = MFMA16x32(aA0, k10##S, acA1); \
  acA1 = MFMA16x32(aA1, k11##S, acA1); \
  acB1 = MFMA16x32(aB0, k10##S, acB1); \
  acB1 = MFMA16x32(aB1, k11##S, acB1); \
  _Pragma("unroll") for (int e = 0; e < 4; e++) { \
    float pA0 = ((mwA[e] >> c) & 1u) ? 0.0f : __expf(acA0[e]); \
    float pA1 = ((mwA[e] >> (16 + c)) & 1u) ? 0.0f : __expf(acA1[e]); \
    float pB0 = ((mwB[e] >> c) & 1u) ? 0.0f : __expf(acB0[e]); \
    float pB1 = ((mwB[e] >> (16 + c)) & 1u) ? 0.0f : __expf(acB1[e]); \
    ZsA[e] += pA0 + pA1; \
    ZsB[e] += pB0 + pB1; } }

#define P2SUB(KT, S) { \
  unsigned int mwA[4], mwB[4]; \
  _Pragma("unroll") for (int e = 0; e < 4; e++) { \
    mwA[e] = bq[(size_t)(g * 4 + e) * (S_LEN / 32) + (KT)]; \
    mwB[e] = bq[(size_t)(16 + g * 4 + e) * (S_LEN / 32) + (KT)]; } \
  half8 vb0 = *(const half8*)(Vb + (size_t)(0 * 16 + c) * S_LEN + (KT) * 32 + g * 8); \
  half8 vb1 = *(const half8*)(Vb + (size_t)(1 * 16 + c) * S_LEN + (KT) * 32 + g * 8); \
  half8 vb2 = *(const half8*)(Vb + (size_t)(2 * 16 + c) * S_LEN + (KT) * 32 + g * 8); \
  half8 vb3 = *(const half8*)(Vb + (size_t)(3 * 16 + c) * S_LEN + (KT) * 32 + g * 8); \
  f32x4 acA0 = (f32x4)0.0f, acA1 = (f32x4)0.0f; \
  f32x4 acB0 = (f32x4)0.0f, acB1 = (f32x4)0.0f; \
  acA0 = MFMA16x32(aA0, k00##S, acA0); \
  acA0 = MFMA16x32(aA1, k01##S, acA0); \
  acB0 = MFMA16x32(aB0, k00##S, acB0); \
  acB0 = MFMA16x32(aB1, k01##S, acB0); \
  acA1 = MFMA16x32(aA0, k10##S, acA1); \
  acA1 = MFMA16x32(aA1, k11##S, acA1); \
  acB1 = MFMA16x32(aB0, k10##S, acB1); \
  acB1 = MFMA16x32(aB1, k11##S, acB1); \
  _Pragma("unroll") for (int e = 0; e < 4; e++) { \
    float pA0 = ((mwA[e] >> c) & 1u) ? 0.0f : __expf(acA0[e] - lZA[e]); \
    float pA1 = ((mwA[e] >> (16 + c)) & 1u) ? 0.0f : __expf(acA1[e] - lZA[e]); \
    float pB0 = ((mwB[e] >> c) & 1u) ? 0.0f : __expf(acB0[e] - lZB[e]); \
    float pB1 = ((mwB[e] >> (16 + c)) & 1u) ? 0.0f : __expf(acB1[e] - lZB[e]); \
    pbuf[w][g * 4 + e][c] = (_Float16)pA0; \
    pbuf[w][g * 4 + e][16 + c] = (_Float16)pA1; \
    pbuf[w][16 + g * 4 + e][c] = (_Float16)pB0; \
    pbuf[w][16 + g * 4 + e][16 + c] = (_Float16)pB1; } \
  half8 paA = *(const half8*)&pbuf[w][c][g * 8]; \
  half8 paB = *(const half8*)&pbuf[w][16 + c][g * 8]; \
  _Pragma("unroll") for (int s = 0; s < 4; s++) { \
    const int r = (lane >> 3) + s * 8; \
    const int c4 = (lane & 7) * 4; \
    half4 h = *(const half4*)&pbuf[w][r][c4]; \
    f32x4 o; \
    _Pragma("unroll") for (int j = 0; j < 4; j++) o[j] = (float)h[j]; \
    __builtin_nontemporal_store(o, \
        (f32x4*)(attn_base + (size_t)r * S_LEN + (KT) * 32 + c4)); } \
  ctxA[0] = MFMA16x32(paA, vb0, ctxA[0]); \
  ctxB[0] = MFMA16x32(paB, vb0, ctxB[0]); \
  ctxA[1] = MFMA16x32(paA, vb1, ctxA[1]); \
  ctxB[1] = MFMA16x32(paB, vb1, ctxB[1]); \
  ctxA[2] = MFMA16x32(paA, vb2, ctxA[2]); \
  ctxB[2] = MFMA16x32(paB, vb2, ctxB[2]); \
  ctxA[3] = MFMA16x32(paA, vb3, ctxA[3]); \
  ctxB[3] = MFMA16x32(paB, vb3, ctxB[3]); }

__global__ __launch_bounds__(512, 2)
void attn_v10_kernel(const _Float16* __restrict__ QH, const _Float16* __restrict__ KH,
                     const _Float16* __restrict__ VT, const unsigned int* __restrict__ bits,
                     float* __restrict__ out) {
  __shared__ __align__(16) _Float16 pbuf[8][32][40];
  __shared__ float zbuf[4][2][32];
  __shared__ __align__(16) float cbuf[4][32][64];

  const int tid = threadIdx.x;
  const int w = tid >> 6;
  const int lane = tid & 63;
  const int g = lane >> 4;
  const int c = lane & 15;
  const int tb = w >> 1;
  const int half = w & 1;

  const int phys = blockIdx.x;
  const int orig = (phys & 7) * 64 + (phys >> 3);
  const int tile = orig * 4 + tb;
  const int bh = tile >> 6;
  const int q0 = (tile & 63) << 5;

  const _Float16* qpA = QH + ((size_t)(bh * S_LEN + q0 + c)) * DKV + g * 8;
  const half8 aA0 = *(const half8*)qpA;
  const half8 aA1 = *(const half8*)(qpA + 32);
  const _Float16* qpB = qpA + 16 * DKV;
  const half8 aB0 = *(const half8*)qpB;
  const half8 aB1 = *(const half8*)(qpB + 32);

  const _Float16* Kb = KH + (size_t)bh * S_LEN * DKV;
  const unsigned int* bq = bits + ((size_t)(bh * S_LEN + q0)) * (S_LEN / 32);

  float ZsA[4] = {0.0f, 0.0f, 0.0f, 0.0f};
  float ZsB[4] = {0.0f, 0.0f, 0.0f, 0.0f};

  const int kt0 = half * 32;
  half8 k00a, k01a, k10a, k11a, k00b, k01b, k10b, k11b;

  // ---------------- pass 1: Z = sum over unmasked exp(s), pipelined --------
  LOADF(a, kt0);
  for (int sp = 0; sp < 16; ++sp) {
    const int s0 = kt0 + sp * 2;
    LOADF(b, s0 + 1);
    P1SUB(s0, a);
    if (sp < 15) LOADF(a, s0 + 2);
    P1SUB(s0 + 1, b);
  }

#pragma unroll
  for (int off = 1; off < 16; off <<= 1) {
#pragma unroll
    for (int e = 0; e < 4; e++) {
      ZsA[e] += __shfl_xor(ZsA[e], off, 64);
      ZsB[e] += __shfl_xor(ZsB[e], off, 64);
    }
  }
  if (c == 0) {
#pragma unroll
    for (int e = 0; e < 4; e++) {
      zbuf[tb][half][g * 4 + e] = ZsA[e];
      zbuf[tb][half][16 + g * 4 + e] = ZsB[e];
    }
  }
  __syncthreads();
  float lZA[4], lZB[4];
#pragma unroll
  for (int e = 0; e < 4; e++) {
    lZA[e] = __logf(zbuf[tb][0][g * 4 + e] + zbuf[tb][1][g * 4 + e]);
    lZB[e] = __logf(zbuf[tb][0][16 + g * 4 + e] + zbuf[tb][1][16 + g * 4 + e]);
  }

  // ---------------- pass 2: attn = exp(s - lnZ), PV, pipelined -------------
  f32x4 ctxA[4], ctxB[4];
#pragma unroll
  for (int nn = 0; nn < 4; nn++) { ctxA[nn] = (f32x4)0.0f; ctxB[nn] = (f32x4)0.0f; }

  const _Float16* Vb = VT + (size_t)bh * DKV * S_LEN;
  float* attn_base = out + CTX_ELEMS + ((size_t)(bh * S_LEN + q0)) * S_LEN;

  LOADF(a, kt0);
  for (int sp = 0; sp < 16; ++sp) {
    const int s0 = kt0 + sp * 2;
    LOADF(b, s0 + 1);
    P2SUB(s0, a);
    if (sp < 15) LOADF(a, s0 + 2);
    P2SUB(s0 + 1, b);
  }

  // ---------------- ctx combine across the two halves ----------------------
  __syncthreads();
  if (half == 1) {
#pragma unroll
    for (int nn = 0; nn < 4; nn++) {
#pragma unroll
      for (int e = 0; e < 4; e++) {
        cbuf[tb][g * 4 + e][nn * 16 + c] = ctxA[nn][e];
        cbuf[tb][16 + g * 4 + e][nn * 16 + c] = ctxB[nn][e];
      }
    }
  }
  __syncthreads();
  if (half == 0) {
    float* cb = out + ((size_t)(bh * S_LEN + q0)) * DKV;
#pragma unroll
    for (int nn = 0; nn < 4; nn++) {
#pragma unroll
      for (int e = 0; e < 4; e++) {
        float vA = ctxA[nn][e] + cbuf[tb][g * 4 + e][nn * 16 + c];
        float vB = ctxB[nn][e] + cbuf[tb][16 + g * 4 + e][nn * 16 + c];
        __builtin_nontemporal_store(vA, cb + (size_t)(g * 4 + e) * DKV + nn * 16 + c);
        __builtin_nontemporal_store(vB, cb + (size_t)(16 + g * 4 + e) * DKV + nn * 16 + c);
      }
    }
  }
}

// ---------------------------------------------------------------------------
// Fallback (R1 kernel) if ws is too small.
// ---------------------------------------------------------------------------
__global__ __launch_bounds__(512, 1)
void attn_slow_kernel(const float* __restrict__ Q, const float* __restrict__ K,
                      const float* __restrict__ V, const void* __restrict__ maskv,
                      float* __restrict__ out, const int* __restrict__ flag) {
  __shared__ __align__(16) unsigned char smem[16 * 2056 * 2];
  __shared__ float redm[8][16];
  __shared__ float reds[8][16];
  _Float16 (*P)[2056] = (_Float16 (*)[2056])smem;

  const int bh = blockIdx.y;
  const int q0 = blockIdx.x << 4;
  const int tid = threadIdx.x;
  const int w = tid >> 6;
  const int lane = tid & 63;
  const int g = lane >> 4;
  const int c = lane & 15;
  const int k0 = w << 8;

  const bool mask_w = (*flag) != 0;
  const unsigned char* m8 = (const unsigned char*)maskv;
  const unsigned int* m32 = (const unsigned int*)maskv;

  const float* Qb = Q + ((size_t)bh * S_LEN + q0) * DKV;
  const float* Kb = K + (size_t)bh * S_LEN * DKV;
  const float* Vb = V + (size_t)bh * S_LEN * DKV;
  const size_t mbase = ((size_t)bh * S_LEN + q0) * S_LEN;
  float* ctx_out = out + ((size_t)bh * S_LEN + q0) * DKV;
  float* attn_out = out + CTX_ELEMS + mbase;

  half8 a0, a1;
  {
    const float* qrow = Qb + (size_t)c * DKV + g * 8;
    f32x4 x0 = *(const f32x4*)(qrow);
    f32x4 x1 = *(const f32x4*)(qrow + 4);
    f32x4 y0 = *(const f32x4*)(qrow + 32);
    f32x4 y1 = *(const f32x4*)(qrow + 36);
#pragma unroll
    for (int j = 0; j < 4; j++) {
      a0[j] = (_Float16)x0[j]; a0[4 + j] = (_Float16)x1[j];
      a1[j] = (_Float16)y0[j]; a1[4 + j] = (_Float16)y1[j];
    }
  }

  f32x4 acc[16];
#pragma unroll
  for (int n = 0; n < 16; n++) acc[n] = (f32x4)0.0f;
#pragma unroll
  for (int n = 0; n < 16; n++) {
    const float* kr = Kb + (size_t)(k0 + n * 16 + c) * DKV + g * 8;
    f32x4 x0 = *(const f32x4*)(kr);
    f32x4 x1 = *(const f32x4*)(kr + 4);
    f32x4 y0 = *(const f32x4*)(kr + 32);
    f32x4 y1 = *(const f32x4*)(kr + 36);
    half8 b0, b1;
#pragma unroll
    for (int j = 0; j < 4; j++) {
      b0[j] = (_Float16)x0[j]; b0[4 + j] = (_Float16)x1[j];
      b1[j] = (_Float16)y0[j]; b1[4 + j] = (_Float16)y1[j];
    }
    acc[n] = MFMA16x32(a0, b0, acc[n]);
    acc[n] = MFMA16x32(a1, b1, acc[n]);
  }

  float mx[4] = {-1e9f, -1e9f, -1e9f, -1e9f};
#pragma unroll
  for (int n = 0; n < 16; n++) {
    const int kc = k0 + n * 16 + c;
#pragma unroll
    for (int e = 0; e < 4; e++) {
      const size_t mi = mbase + (size_t)(g * 4 + e) * S_LEN + kc;
      bool masked;
      if (mask_w) masked = (__builtin_nontemporal_load(&m32[mi]) != 0u);
      else        masked = (__builtin_nontemporal_load(&m8[mi]) != 0);
      float s = masked ? -1e9f : acc[n][e] * 0.125f;
      acc[n][e] = s;
      mx[e] = fmaxf(mx[e], s);
    }
  }
#pragma unroll
  for (int off = 1; off < 16; off <<= 1) {
#pragma unroll
    for (int e = 0; e < 4; e++)
      mx[e] = fmaxf(mx[e], __shfl_xor(mx[e], off, 64));
  }
  if (c == 0) {
#pragma unroll
    for (int e = 0; e < 4; e++) redm[w][g * 4 + e] = mx[e];
  }
  __syncthreads();
  float m[4], sm[4];
#pragma unroll
  for (int e = 0; e < 4; e++) {
    float v = redm[0][g * 4 + e];
#pragma unroll
    for (int ww = 1; ww < 8; ww++) v = fmaxf(v, redm[ww][g * 4 + e]);
    m[e] = v;
    sm[e] = 0.0f;
  }
#pragma unroll
  for (int n = 0; n < 16; n++) {
#pragma unroll
    for (int e = 0; e < 4; e++) {
      float p = __expf(acc[n][e] - m[e]);
      acc[n][e] = p;
      sm[e] += p;
    }
  }
#pragma unroll
  for (int off = 1; off < 16; off <<= 1) {
#pragma unroll
    for (int e = 0; e < 4; e++) sm[e] += __shfl_xor(sm[e], off, 64);
  }
  if (c == 0) {
#pragma unroll
    for (int e = 0; e < 4; e++) reds[w][g * 4 + e] = sm[e];
  }
  __syncthreads();
  float inv[4];
#pragma unroll
  for (int e = 0; e < 4; e++) {
    float z = 0.0f;
#pragma unroll
    for (int ww = 0; ww < 8; ww++) z += reds[ww][g * 4 + e];
    inv[e] = 1.0f / z;
  }
#pragma unroll
  for (int n = 0; n < 16; n++) {
    const int kc = k0 + n * 16 + c;
#pragma unroll
    for (int e = 0; e < 4; e++) {
      float v = acc[n][e] * inv[e];
      __builtin_nontemporal_store(v, &attn_out[(size_t)(g * 4 + e) * S_LEN + kc]);
      P[g * 4 + e][kc] = (_Float16)v;
    }
  }
  __syncthreads();

  f32x4 ctx[4];
#pragma unroll
  for (int n = 0; n < 4; n++) ctx[n] = (f32x4)0.0f;
  for (int ks = 0; ks < 8; ks++) {
    const int kb = k0 + ks * 32;
    half8 pa = *(const half8*)&P[c][kb + g * 8];
#pragma unroll
    for (int n = 0; n < 4; n++) {
      const float* vp = Vb + (size_t)(kb + g * 8) * DKV + n * 16 + c;
      half8 vb;
#pragma unroll
      for (int j = 0; j < 8; j++) vb[j] = (_Float16)vp[(size_t)j * DKV];
      ctx[n] = MFMA16x32(pa, vb, ctx[n]);
    }
  }
  __syncthreads();

  float* red2 = (float*)smem;
#pragma unroll
  for (int n = 0; n < 4; n++) {
#pragma unroll
    for (int e = 0; e < 4; e++)
      red2[((w * 16) + g * 4 + e) * 64 + n * 16 + c] = ctx[n][e];
  }
  __syncthreads();
  for (int i = tid; i < 16 * 64; i += 512) {
    int q = i >> 6, d = i & 63;
    float ssum = 0.0f;
#pragma unroll
    for (int ww = 0; ww < 8; ww++) ssum += red2[((ww * 16) + q) * 64 + d];
    ctx_out[(size_t)q * DKV + d] = ssum;
  }
}

extern "C" void kernel_launch(void* const* d_in, const int* in_sizes, int n_in,
                              void* d_out, int out_size, void* d_ws, size_t ws_size,
                              hipStream_t stream) {
  (void)in_sizes; (void)n_in; (void)out_size;
  const float* Q = (const float*)d_in[0];
  const float* K = (const float*)d_in[1];
  const float* V = (const float*)d_in[2];
  const void* mask = d_in[3];

  const size_t HBYTES = (size_t)NBH * S_LEN * DKV * sizeof(_Float16);       // 8 MB
  const size_t BITBYTES = (size_t)NBH * S_LEN * (S_LEN / 32) * 4;           // 16 MB
  const size_t NEED = 256 + 3 * HBYTES + BITBYTES;

  int* flag = (int*)d_ws;
  hipLaunchKernelGGL(detect_mask_kernel, dim3(1), dim3(512), 0, stream,
                     (const unsigned char*)mask, flag);

  if (ws_size >= NEED) {
    _Float16* QH = (_Float16*)((char*)d_ws + 256);
    _Float16* KH = (_Float16*)((char*)d_ws + 256 + HBYTES);
    _Float16* VT = (_Float16*)((char*)d_ws + 256 + 2 * HBYTES);
    unsigned int* bits = (unsigned int*)((char*)d_ws + 256 + 3 * HBYTES);
    hipLaunchKernelGGL(fused_pre_kernel,
                       dim3(PACK_B + 2 * CONV_B + (S_LEN / 64) * NBH), dim3(256), 0, stream,
                       mask, flag, bits, Q, QH, K, KH, V, VT);
    hipLaunchKernelGGL(attn_v10_kernel, dim3(512), dim3(512), 0, stream,
                       QH, KH, VT, bits, (float*)d_out);
  } else {
    hipLaunchKernelGGL(attn_slow_kernel, dim3(128, 32), dim3(512), 0, stream,
                       Q, K, V, mask, (float*)d_out, flag);
  }
}